// Round 1
// baseline (361.948 us; speedup 1.0000x reference)
//
#include <hip/hip_runtime.h>
#include <hip/hip_bf16.h>
#include <stdint.h>

typedef _Float16 f16;
typedef _Float16 f16x8 __attribute__((ext_vector_type(8)));
typedef float f32x16 __attribute__((ext_vector_type(16)));
typedef float f32x4 __attribute__((ext_vector_type(4)));

// async global->LDS, 16B per lane, lands at ldsbase + lane*16
#define GLL16(gp, lp)                                                          \
  __builtin_amdgcn_global_load_lds(                                            \
      (const __attribute__((address_space(1))) void*)(gp),                     \
      (__attribute__((address_space(3))) void*)(lp), 16, 0, 0)

// s_waitcnt vmcnt(N), lgkm/exp unconstrained. gfx9 encoding:
// vmcnt[3:0]=bits3:0, vmcnt[5:4]=bits15:14, exp=bits6:4, lgkm=bits11:8
#define WAITCNT_VM(N)                                                          \
  __builtin_amdgcn_s_waitcnt(((N)&0xF) | ((((N) >> 4) & 3) << 14) | 0x0F70)

// ---------------------------------------------------------------------------
// Kernel 1: x NCHW f32 [32,256,64,64] -> xt NHWC f16 [32,64,64,256]
// Per block: one (b,h) slice. LDS tile [w=64][c=256] with granule rotation
// swizzle to keep both phases <=2-way bank conflicts (free per m136).
// ---------------------------------------------------------------------------
__global__ __launch_bounds__(256) void nchw_to_nhwc_f16(
    const float* __restrict__ x, f16* __restrict__ xt) {
  __shared__ __align__(16) f16 tile[64 * 264];
  const int bh = blockIdx.x;  // b*64 + h
  const int t = threadIdx.x;
  const float* src = x + (size_t)(bh >> 6) * (256 * 4096) + (bh & 63) * 64;

  const int w4 = t & 15;      // float4 index along w
  const int cl = t >> 4;      // c offset 0..15
#pragma unroll
  for (int it = 0; it < 16; ++it) {
    const int c = it * 16 + cl;
    const float4 v = *(const float4*)(src + (size_t)c * 4096 + w4 * 4);
    const int g = c >> 3;     // c-granule
    const int c7 = c & 7;
    const float vv[4] = {v.x, v.y, v.z, v.w};
#pragma unroll
    for (int j = 0; j < 4; ++j) {
      const int w = w4 * 4 + j;
      const int rot = (g + (w >> 3)) & 31;
      tile[w * 264 + rot * 8 + c7] = (f16)vv[j];
    }
  }
  __syncthreads();
  f16* dst = xt + (size_t)bh * 16384;
#pragma unroll
  for (int it = 0; it < 8; ++it) {
    const int idx = it * 256 + t;  // 0..2047 granules
    const int w = idx >> 5;
    const int g = idx & 31;
    const int rot = (g + (w >> 3)) & 31;
    const f16x8 vv = *(const f16x8*)&tile[w * 264 + rot * 8];
    *(f16x8*)(dst + idx * 8) = vv;
  }
}

// ---------------------------------------------------------------------------
// Kernel 2: W [32co][256ci][9][9] f32 -> Wt [81 khkw][32 co][256 ci] f16
// ---------------------------------------------------------------------------
__global__ __launch_bounds__(256) void pack_w(const float* __restrict__ W,
                                              f16* __restrict__ wt) {
  const int o = blockIdx.x * 256 + threadIdx.x;  // 663552 total, exact grid
  const int khkw = o >> 13;
  const int rem = o & 8191;
  const int co = rem >> 8;
  const int ci = rem & 255;
  wt[o] = (f16)W[(co * 256 + ci) * 81 + khkw];
}

// ---------------------------------------------------------------------------
// Kernel 3: implicit-GEMM conv via mfma_f32_32x32x16_f16.
// grid 784 = 392 M64-tiles x 2 khkw-halves. 4 waves/block, each wave owns
// ~10 of its half's 9x9 taps (K-split), wave-autonomous K-loop:
// global_load_lds double-buffer + s_waitcnt vmcnt(6), NO barriers in loop.
// Ends: LDS reduction over 4 waves -> convp[khalf][pixel*32+co].
// ---------------------------------------------------------------------------
__global__ __launch_bounds__(256) void conv_gemm(const f16* __restrict__ xt,
                                                 const f16* __restrict__ wt,
                                                 float* __restrict__ convp) {
  // per wave: 12288 B = 2 bufs x (A 4096 B [64m x 32ci f16] + B 2048 B [32co x 32ci])
  __shared__ __align__(16) char smem[49152];
  const int tid = threadIdx.x;
  const int lane = tid & 63;
  const int wave = tid >> 6;
  const int blk = blockIdx.x;
  const int mtile = blk >> 1;
  const int khalf = blk & 1;

  // Pixel byte-offsets into xt for the 4 A-staging issues (16 rows each).
  // xt byte addr = (b*4096 + (2oh+kh)*64 + (2ow+kw))*512 + ci*2
  int pb[4];
#pragma unroll
  for (int issue = 0; issue < 4; ++issue) {
    const int r = issue * 16 + (lane >> 2);
    const int p = mtile * 64 + r;  // global pixel, 0..25087 (exact: 392*64)
    const int bi = p / 784;
    const int rm = p - bi * 784;
    const int oh = rm / 28;
    const int ow = rm - oh * 28;
    pb[issue] = (bi * 4096 + oh * 128 + ow * 2) * 512 + (lane & 3) * 16;
  }

  const int kkstart = (khalf ? 41 : 0) + wave;
  const int kkend = khalf ? 81 : 41;
  const int nk = (kkend - kkstart + 3) >> 2;  // taps for this wave
  const int nIt = nk * 8;                     // x 8 ci-chunks of 32

  const char* xtb = (const char*)xt;
  const char* wtb = (const char*)wt;
  char* lws = smem + wave * 12288;

  f32x16 acc0, acc1;
#pragma unroll
  for (int i = 0; i < 16; ++i) { acc0[i] = 0.f; acc1[i] = 0.f; }

  auto stage = [&](int it) {
    const int kk = kkstart + (it >> 3) * 4;
    const int cic = it & 7;
    const int kh = kk / 9;
    const int kw = kk - kh * 9;
    const int kshift = (kh * 64 + kw) * 512 + cic * 64;
    char* lb = lws + (it & 1) * 6144;
#pragma unroll
    for (int issue = 0; issue < 4; ++issue)
      GLL16(xtb + pb[issue] + kshift, lb + issue * 1024);
    const int brow = lane >> 2;
#pragma unroll
    for (int issue = 0; issue < 2; ++issue)
      GLL16(wtb + (size_t)((kk * 32 + brow + issue * 16) * 256 + cic * 32) * 2 +
                (lane & 3) * 16,
            lb + 4096 + issue * 1024);
  };

  stage(0);
  const int ro = (lane & 31) * 64;
  const int qo = (lane >> 5) * 16;
  for (int it = 0; it < nIt; ++it) {
    if (it + 1 < nIt) {
      stage(it + 1);
      WAITCNT_VM(6);  // wait for iter it's 6 loads; it+1's 6 stay in flight
    } else {
      WAITCNT_VM(0);
    }
    __builtin_amdgcn_sched_barrier(0);
    const char* lb = lws + (it & 1) * 6144;
#pragma unroll
    for (int s = 0; s < 2; ++s) {
      const f16x8 bfr = *(const f16x8*)(lb + 4096 + ro + s * 32 + qo);
      const f16x8 a0 = *(const f16x8*)(lb + ro + s * 32 + qo);
      const f16x8 a1 = *(const f16x8*)(lb + 2048 + ro + s * 32 + qo);
      acc0 = __builtin_amdgcn_mfma_f32_32x32x16_f16(a0, bfr, acc0, 0, 0, 0);
      acc1 = __builtin_amdgcn_mfma_f32_32x32x16_f16(a1, bfr, acc1, 0, 0, 0);
    }
  }

  // Cross-wave reduction. Each wave's red region lies inside its own staging
  // region (8704 B < 12288 B) but barrier anyway before the read phase.
  __syncthreads();
  float* red = (float*)smem;  // [wave][m 64][34 pad]
#pragma unroll
  for (int r = 0; r < 16; ++r) {
    const int mrow = (r & 3) + 8 * (r >> 2) + 4 * (lane >> 5);
    red[(wave * 64 + mrow) * 34 + (lane & 31)] = acc0[r];
    red[(wave * 64 + 32 + mrow) * 34 + (lane & 31)] = acc1[r];
  }
  __syncthreads();

  const int m = tid & 63;
  const int cg = tid >> 6;  // co group: co = cg*8 + j
  float v[8];
#pragma unroll
  for (int j = 0; j < 8; ++j) v[j] = 0.f;
#pragma unroll
  for (int w = 0; w < 4; ++w) {
    const float* rp = red + (w * 64 + m) * 34 + cg * 8;
#pragma unroll
    for (int j = 0; j < 8; ++j) v[j] += rp[j];
  }
  const int p = mtile * 64 + m;
  float* op = convp + (size_t)khalf * 802816 + p * 32 + cg * 8;
  f32x4 q0 = {v[0], v[1], v[2], v[3]};
  f32x4 q1 = {v[4], v[5], v[6], v[7]};
  *(f32x4*)op = q0;
  *(f32x4*)(op + 4) = q1;
}

// ---------------------------------------------------------------------------
// Kernel 4: epilogue. v = conv0+conv1+bias; sq=8v^2;
// scale = sq/((1+sq)*sqrt(sq+1e-8)); y=v*scale, broadcast to 8 t-slots.
// out[b][co*784+pix][t], flat = b*200704 + (co*784+pix)*8 + t
// ---------------------------------------------------------------------------
__global__ __launch_bounds__(256) void epilogue(const float* __restrict__ convp,
                                                const float* __restrict__ bias,
                                                float* __restrict__ out) {
  const int g = blockIdx.x * 256 + threadIdx.x;  // 100352 total, exact grid
  const int base = g * 8;
  const int p = g >> 2;           // global pixel
  const int co0 = (g & 3) * 8;
  const int bi = p / 784;
  const int pix = p - bi * 784;
  float v[8];
#pragma unroll
  for (int j = 0; j < 8; ++j)
    v[j] = convp[base + j] + convp[802816 + base + j] + bias[co0 + j];
  float* ob = out + (size_t)bi * 200704 + pix * 8;
#pragma unroll
  for (int j = 0; j < 8; ++j) {
    const float vv = v[j];
    const float sq = 8.f * vv * vv;
    const float scale = sq / ((1.f + sq) * sqrtf(sq + 1e-8f));
    const float y = vv * scale;
    const f32x4 q = {y, y, y, y};
    float* o = ob + (size_t)(co0 + j) * 6272;
    *(f32x4*)o = q;
    *(f32x4*)(o + 4) = q;
  }
}

// ---------------------------------------------------------------------------
extern "C" void kernel_launch(void* const* d_in, const int* in_sizes, int n_in,
                              void* d_out, int out_size, void* d_ws,
                              size_t ws_size, hipStream_t stream) {
  const float* x = (const float*)d_in[0];     // [32,256,64,64]
  const float* W = (const float*)d_in[1];     // [32,256,9,9]
  const float* bias = (const float*)d_in[2];  // [32]
  float* out = (float*)d_out;                 // 6422528 f32

  char* ws = (char*)d_ws;
  f16* xt = (f16*)ws;                                   // 67,108,864 B
  f16* wt = (f16*)(ws + 67108864);                      //  1,327,104 B
  float* convp = (float*)(ws + 67108864 + 1327104);     //  6,422,528 B (2 halves)

  nchw_to_nhwc_f16<<<dim3(2048), dim3(256), 0, stream>>>(x, xt);
  pack_w<<<dim3(2592), dim3(256), 0, stream>>>(W, wt);
  conv_gemm<<<dim3(784), dim3(256), 0, stream>>>(xt, wt, convp);
  epilogue<<<dim3(392), dim3(256), 0, stream>>>(convp, bias, out);
}

// Round 2
// 350.091 us; speedup vs baseline: 1.0339x; 1.0339x over previous
//
#include <hip/hip_runtime.h>
#include <hip/hip_bf16.h>
#include <stdint.h>

typedef _Float16 f16;
typedef _Float16 f16x8 __attribute__((ext_vector_type(8)));
typedef float f32x16 __attribute__((ext_vector_type(16)));
typedef float f32x4 __attribute__((ext_vector_type(4)));
typedef uint32_t u32x4 __attribute__((ext_vector_type(4)));
typedef uint32_t u32x2 __attribute__((ext_vector_type(2)));

// async global->LDS, 16B per lane, lands at ldsbase + lane*16 (wave-uniform base)
#define GLL16(gp, lp)                                                          \
  __builtin_amdgcn_global_load_lds(                                            \
      (const __attribute__((address_space(1))) void*)(gp),                     \
      (__attribute__((address_space(3))) void*)(lp), 16, 0, 0)

// s_waitcnt vmcnt(N), lgkm/exp unconstrained. gfx9 encoding.
#define WAITCNT_VM(N)                                                          \
  __builtin_amdgcn_s_waitcnt(((N)&0xF) | ((((N) >> 4) & 3) << 14) | 0x0F70)

// ---------------------------------------------------------------------------
// Kernel 1: x NCHW f32 [32,256,64,64] -> xt NHWC f16 [32,64,64,256]
// One (b,h) slice per block. Registers pack f16 pairs -> ds_write_b64
// (16 b64 writes/thread vs 64 b16 in v1). Row stride 132 u32 (528 B): keeps
// 16B alignment for b128 reads; read phase is conflict-free, writes ~2-way.
// ---------------------------------------------------------------------------
__global__ __launch_bounds__(256) void nchw_to_nhwc_f16(
    const float* __restrict__ x, f16* __restrict__ xt) {
  __shared__ __align__(16) uint32_t tile[64 * 132];  // 33792 B
  const int bh = blockIdx.x;  // b*64 + h
  const int t = threadIdx.x;
  const float* src = x + (size_t)(bh >> 6) * (256 * 4096) + (bh & 63) * 64;

  const int w4 = t & 15;   // float4 index along w
  const int cq = t >> 4;   // c-quad within 64
#pragma unroll
  for (int it = 0; it < 4; ++it) {
    const int c0 = it * 64 + cq * 4;
    float4 v0 = *(const float4*)(src + (size_t)(c0 + 0) * 4096 + w4 * 4);
    float4 v1 = *(const float4*)(src + (size_t)(c0 + 1) * 4096 + w4 * 4);
    float4 v2 = *(const float4*)(src + (size_t)(c0 + 2) * 4096 + w4 * 4);
    float4 v3 = *(const float4*)(src + (size_t)(c0 + 3) * 4096 + w4 * 4);
    const float* p0 = (const float*)&v0;
    const float* p1 = (const float*)&v1;
    const float* p2 = (const float*)&v2;
    const float* p3 = (const float*)&v3;
#pragma unroll
    for (int jw = 0; jw < 4; ++jw) {
      const int w = w4 * 4 + jw;
      f16 h0 = (f16)p0[jw], h1 = (f16)p1[jw], h2 = (f16)p2[jw], h3 = (f16)p3[jw];
      uint32_t lo = (uint32_t)__builtin_bit_cast(uint16_t, h0) |
                    ((uint32_t)__builtin_bit_cast(uint16_t, h1) << 16);
      uint32_t hi = (uint32_t)__builtin_bit_cast(uint16_t, h2) |
                    ((uint32_t)__builtin_bit_cast(uint16_t, h3) << 16);
      u32x2 pk = {lo, hi};
      *(u32x2*)&tile[w * 132 + (c0 >> 1)] = pk;
    }
  }
  __syncthreads();
  f16* dst = xt + (size_t)bh * 16384;
#pragma unroll
  for (int it = 0; it < 8; ++it) {
    const int idx = it * 256 + t;  // 0..2047 16B-granules
    const int w = idx >> 5;
    const int g = idx & 31;
    const u32x4 v = *(const u32x4*)&tile[w * 132 + g * 4];
    *(u32x4*)(dst + idx * 8) = v;
  }
}

// ---------------------------------------------------------------------------
// Kernel 2: W [32co][256ci][9][9] f32 -> wt [81 kk][8 cic][32 co][32 ci] f16
// (so a wave's B-fragment load is one contiguous 2 KB region)
// ---------------------------------------------------------------------------
__global__ __launch_bounds__(256) void pack_w(const float* __restrict__ W,
                                              f16* __restrict__ wt) {
  const int o = blockIdx.x * 256 + threadIdx.x;  // 663552 total, exact grid
  const int ci5 = o & 31;
  const int co = (o >> 5) & 31;
  const int cic = (o >> 10) & 7;
  const int kk = o >> 13;
  const int ci = cic * 32 + ci5;
  wt[o] = (f16)W[(co * 256 + ci) * 81 + kk];
}

// ---------------------------------------------------------------------------
// Kernel 3: implicit-GEMM conv, mfma_f32_32x32x16_f16.
// 1568 blocks = 392 M64-tiles x 4 k-groups; 4 waves/block, wave owns
// k-chunk range [ (81q)/2, (81(q+1))/2 ), q = kg*4+wave  (40/41 chunks each).
// A: double-buffered global_load_lds (4 KB/buf), XOR-swizzled 16B granules.
// B: direct global->VGPR (L2-hot), prefetched one iter ahead.
// No barriers in K-loop; vmcnt(6) fine-grained wait. 32 KB LDS -> 5 blk/CU.
// ---------------------------------------------------------------------------
__global__ __launch_bounds__(256, 5) void conv_gemm(const f16* __restrict__ xt,
                                                    const f16* __restrict__ wt,
                                                    float* __restrict__ convp) {
  __shared__ __align__(16) char smem[32768];
  const int tid = threadIdx.x;
  const int lane = tid & 63;
  const int wave = tid >> 6;
  const int blk = blockIdx.x;
  // XCD-aware swizzle: each XCD gets contiguous mtiles (L2 locality)
  const int xcd = blk & 7;
  const int j = blk >> 3;          // 0..195
  const int kg = j / 49;           // 0..3
  const int mtile = xcd * 49 + (j - kg * 49);
  const int q = kg * 4 + wave;     // 0..15
  const int cstart = (81 * q) >> 1;
  const int nIt = ((81 * (q + 1)) >> 1) - cstart;  // 40 or 41

  // A staging: lane holds granule g of row r=lane>>2 (+16/issue), at LDS pos
  // lane*16. Swizzle: pos holds granule ((pos&3)-(r&3))&3 -> bank-uniform reads.
  const int g = ((lane & 3) - ((lane >> 2) & 3)) & 3;
  int pb[4];
#pragma unroll
  for (int i = 0; i < 4; ++i) {
    const int r = i * 16 + (lane >> 2);
    const int p = mtile * 64 + r;  // 0..25087 exact
    const int bi = p / 784;
    const int rm = p - bi * 784;
    const int oh = rm / 28;
    const int ow = rm - oh * 28;
    pb[i] = (bi * 4096 + oh * 128 + ow * 2) * 512 + g * 16;
  }
  const char* xtb = (const char*)xt;
  const char* wtb = (const char*)wt;
  char* lws = smem + wave * 8192;

  const int r0 = lane & 31;
  const int h = lane >> 5;
  const int offA0 = r0 * 64 + (((0 + h) + r0) & 3) * 16;  // s=0 fragment
  const int offA1 = r0 * 64 + (((2 + h) + r0) & 3) * 16;  // s=1 fragment
  const int blane = r0 * 64 + h * 16;  // B: n*64 + h*16 within 2 KB chunk

  f32x16 acc0, acc1;
#pragma unroll
  for (int i = 0; i < 16; ++i) { acc0[i] = 0.f; acc1[i] = 0.f; }

  auto stage = [&](int c, int par) {
    const int kk = c >> 3;
    const int cic = c & 7;
    const int kh = (kk * 57) >> 9;  // kk/9 for kk<=80
    const int kw = kk - kh * 9;
    const int koff = (kh * 64 + kw) * 512 + cic * 64;
    char* lb = lws + par * 4096;
#pragma unroll
    for (int i = 0; i < 4; ++i) GLL16(xtb + (pb[i] + koff), lb + i * 1024);
  };
  auto bload = [&](int c, int s) -> f16x8 {
    const int kk = c >> 3;
    const int cic = c & 7;
    return *(const f16x8*)(wtb + kk * 16384 + cic * 2048 + blane + s * 32);
  };

  int c = cstart;
  stage(c, 0);
  f16x8 bc0 = bload(c, 0), bc1 = bload(c, 1);
  for (int it = 0; it < nIt; ++it) {
    const int par = it & 1;
    f16x8 bn0, bn1;
    if (it + 1 < nIt) {
      stage(c + 1, par ^ 1);
      bn0 = bload(c + 1, 0);
      bn1 = bload(c + 1, 1);
      WAITCNT_VM(6);  // 6 newest (next iter) stay in flight
    } else {
      WAITCNT_VM(0);
    }
    __builtin_amdgcn_sched_barrier(0);
    const char* lb = lws + par * 4096;
    const f16x8 a00 = *(const f16x8*)(lb + offA0);
    const f16x8 a10 = *(const f16x8*)(lb + 2048 + offA0);
    acc0 = __builtin_amdgcn_mfma_f32_32x32x16_f16(a00, bc0, acc0, 0, 0, 0);
    acc1 = __builtin_amdgcn_mfma_f32_32x32x16_f16(a10, bc0, acc1, 0, 0, 0);
    const f16x8 a01 = *(const f16x8*)(lb + offA1);
    const f16x8 a11 = *(const f16x8*)(lb + 2048 + offA1);
    acc0 = __builtin_amdgcn_mfma_f32_32x32x16_f16(a01, bc1, acc0, 0, 0, 0);
    acc1 = __builtin_amdgcn_mfma_f32_32x32x16_f16(a11, bc1, acc1, 0, 0, 0);
    bc0 = bn0;
    bc1 = bn1;
    ++c;
  }

  // Block reduction over 4 waves, two rounds (acc0 then acc1).
  // red[4][32][33] f32 = 16896 B (inside 32 KB smem). Stride 33: conflict-free.
  __syncthreads();
  float* red = (float*)smem;
  const int col = lane & 31;
  const int rowbase = 4 * h;
  const int mm = tid >> 3;        // 0..31
  const int c0 = (tid & 7) * 4;   // 0..28
#pragma unroll
  for (int half = 0; half < 2; ++half) {
#pragma unroll
    for (int rI = 0; rI < 16; ++rI) {
      const int row = (rI & 3) + 8 * (rI >> 2) + rowbase;
      red[(wave * 32 + row) * 33 + col] = half ? acc1[rI] : acc0[rI];
    }
    __syncthreads();
    float s0 = 0.f, s1 = 0.f, s2 = 0.f, s3 = 0.f;
#pragma unroll
    for (int w = 0; w < 4; ++w) {
      const float* rp = red + (w * 32 + mm) * 33 + c0;
      s0 += rp[0]; s1 += rp[1]; s2 += rp[2]; s3 += rp[3];
    }
    const f32x4 o4 = {s0, s1, s2, s3};
    *(f32x4*)&convp[(size_t)kg * 802816 + (size_t)(mtile * 64 + half * 32 + mm) * 32 + c0] = o4;
    __syncthreads();
  }
}

// ---------------------------------------------------------------------------
// Kernel 4: epilogue. v = sum(4 partials)+bias; sq=8v^2;
// scale = sq/((1+sq)*sqrt(sq+1e-8)); y=v*scale broadcast to 8 t-slots.
// ---------------------------------------------------------------------------
__global__ __launch_bounds__(256) void epilogue(const float* __restrict__ convp,
                                                const float* __restrict__ bias,
                                                float* __restrict__ out) {
  const int gi = blockIdx.x * 256 + threadIdx.x;  // 100352 total, exact grid
  const int base = gi * 8;
  const int p = gi >> 2;
  const int co0 = (gi & 3) * 8;
  const int bi = p / 784;
  const int pix = p - bi * 784;
  f32x4 v0 = {0.f, 0.f, 0.f, 0.f}, v1 = {0.f, 0.f, 0.f, 0.f};
#pragma unroll
  for (int qq = 0; qq < 4; ++qq) {
    v0 += *(const f32x4*)&convp[(size_t)qq * 802816 + base];
    v1 += *(const f32x4*)&convp[(size_t)qq * 802816 + base + 4];
  }
  float vb[8];
#pragma unroll
  for (int jj = 0; jj < 4; ++jj) {
    vb[jj] = v0[jj] + bias[co0 + jj];
    vb[4 + jj] = v1[jj] + bias[co0 + 4 + jj];
  }
  float* ob = out + (size_t)bi * 200704 + pix * 8;
#pragma unroll
  for (int jj = 0; jj < 8; ++jj) {
    const float vv = vb[jj];
    const float sq = 8.f * vv * vv;
    const float scale = sq / ((1.f + sq) * sqrtf(sq + 1e-8f));
    const float y = vv * scale;
    const f32x4 qv = {y, y, y, y};
    float* o = ob + (size_t)(co0 + jj) * 6272;
    *(f32x4*)o = qv;
    *(f32x4*)(o + 4) = qv;
  }
}

// ---------------------------------------------------------------------------
extern "C" void kernel_launch(void* const* d_in, const int* in_sizes, int n_in,
                              void* d_out, int out_size, void* d_ws,
                              size_t ws_size, hipStream_t stream) {
  const float* x = (const float*)d_in[0];     // [32,256,64,64]
  const float* W = (const float*)d_in[1];     // [32,256,9,9]
  const float* bias = (const float*)d_in[2];  // [32]
  float* out = (float*)d_out;                 // 6422528 f32

  char* ws = (char*)d_ws;
  f16* xt = (f16*)ws;                                // 67,108,864 B
  f16* wt = (f16*)(ws + 67108864);                   //  1,327,104 B
  float* convp = (float*)(ws + 67108864 + 1327104);  // 12,845,056 B (4 partials)

  nchw_to_nhwc_f16<<<dim3(2048), dim3(256), 0, stream>>>(x, xt);
  pack_w<<<dim3(2592), dim3(256), 0, stream>>>(W, wt);
  conv_gemm<<<dim3(1568), dim3(256), 0, stream>>>(xt, wt, convp);
  epilogue<<<dim3(392), dim3(256), 0, stream>>>(convp, bias, out);
}